// Round 1
// baseline (407.213 us; speedup 1.0000x reference)
//
#include <hip/hip_runtime.h>

#define N_NODES 50000
#define DIM 128
#define NH 4
#define DH 32
#define NE 800000
#define SCALEF 0.17677669529663688f   // 1/sqrt(32)

// ---------------- GEMM: C[m][o] = sum_k A[m][k]*W[o][k] + bias[o] (+X[m][o]) ----------------
// A: [M,128] row-major, W: [128,128] row-major (so C = A @ W^T), 128x128 block tile,
// 8x8 micro-tile per thread, K staged in chunks of 32 (transposed [kk][dim] in LDS).
template<bool RESID>
__global__ __launch_bounds__(256)
void gemm_nt_128(const float* __restrict__ A, const float* __restrict__ W,
                 const float* __restrict__ bias, const float* __restrict__ X,
                 float* __restrict__ C, int M)
{
    __shared__ float At[32][132];   // [kk][row]  (pad 132 -> broadcast reads conflict-free)
    __shared__ float Wt[32][132];   // [kk][o]
    const int tid = threadIdx.x;
    const int m0  = blockIdx.x * 128;
    const int tx  = tid & 15, ty = tid >> 4;
    const int c4  = tid & 7;        // k-quad in chunk
    const int r0  = tid >> 3;       // 0..31

    float acc[8][8] = {};

    for (int kc = 0; kc < 128; kc += 32) {
        #pragma unroll
        for (int rr = 0; rr < 4; ++rr) {
            const int r = r0 + rr * 32;          // 0..127
            const int row = m0 + r;
            float4 a = make_float4(0.f, 0.f, 0.f, 0.f);
            if (row < M) a = *(const float4*)(A + (size_t)row * DIM + kc + c4 * 4);
            At[c4*4+0][r] = a.x; At[c4*4+1][r] = a.y;
            At[c4*4+2][r] = a.z; At[c4*4+3][r] = a.w;
            const float4 w = *(const float4*)(W + (size_t)r * DIM + kc + c4 * 4);
            Wt[c4*4+0][r] = w.x; Wt[c4*4+1][r] = w.y;
            Wt[c4*4+2][r] = w.z; Wt[c4*4+3][r] = w.w;
        }
        __syncthreads();
        #pragma unroll
        for (int kk = 0; kk < 32; ++kk) {
            float a[8], b[8];
            *(float4*)&a[0] = *(const float4*)&At[kk][ty * 8];
            *(float4*)&a[4] = *(const float4*)&At[kk][ty * 8 + 4];
            *(float4*)&b[0] = *(const float4*)&Wt[kk][tx * 8];
            *(float4*)&b[4] = *(const float4*)&Wt[kk][tx * 8 + 4];
            #pragma unroll
            for (int i = 0; i < 8; ++i)
                #pragma unroll
                for (int j = 0; j < 8; ++j)
                    acc[i][j] = fmaf(a[i], b[j], acc[i][j]);
        }
        __syncthreads();
    }

    #pragma unroll
    for (int i = 0; i < 8; ++i) {
        const int row = m0 + ty * 8 + i;
        if (row >= M) continue;
        #pragma unroll
        for (int j4 = 0; j4 < 8; j4 += 4) {
            const int o = tx * 8 + j4;
            float4 c;
            c.x = acc[i][j4+0]; c.y = acc[i][j4+1];
            c.z = acc[i][j4+2]; c.w = acc[i][j4+3];
            const float4 bv = *(const float4*)(bias + o);
            c.x += bv.x; c.y += bv.y; c.z += bv.z; c.w += bv.w;
            if (RESID) {
                const float4 xv = *(const float4*)(X + (size_t)row * DIM + o);
                c.x += xv.x; c.y += xv.y; c.z += xv.z; c.w += xv.w;
            }
            *(float4*)(C + (size_t)row * DIM + o) = c;
        }
    }
}

// ---------------- CSR build: histogram -> scan -> scatter ----------------
__global__ __launch_bounds__(256)
void hist_kernel(const int* __restrict__ tgt, int* __restrict__ deg)
{
    const int e = blockIdx.x * 256 + threadIdx.x;
    if (e < NE) atomicAdd(&deg[tgt[e]], 1);
}

__global__ __launch_bounds__(256)
void block_sums(const int* __restrict__ deg, int* __restrict__ bsum, int n)
{
    __shared__ int acc4[4];
    const int b0 = blockIdx.x * 1024;
    int sum = 0;
    for (int i = threadIdx.x; i < 1024; i += 256) {
        const int g = b0 + i;
        sum += (g < n) ? deg[g] : 0;
    }
    #pragma unroll
    for (int w = 1; w < 64; w <<= 1) sum += __shfl_xor(sum, w);
    if ((threadIdx.x & 63) == 0) acc4[threadIdx.x >> 6] = sum;
    __syncthreads();
    if (threadIdx.x == 0) bsum[blockIdx.x] = acc4[0] + acc4[1] + acc4[2] + acc4[3];
}

__global__ void scan_bsum(int* __restrict__ bsum, int* __restrict__ offs_end, int nb)
{
    const int lane = threadIdx.x;           // 64 threads, 1 block
    const int v = (lane < nb) ? bsum[lane] : 0;
    int incl = v;
    #pragma unroll
    for (int w = 1; w < 64; w <<= 1) {
        const int t = __shfl_up(incl, w);
        if (lane >= w) incl += t;
    }
    if (lane < nb) bsum[lane] = incl - v;   // exclusive
    if (lane == 63) offs_end[0] = incl;     // total == NE
}

__global__ __launch_bounds__(1024)
void block_scan(const int* __restrict__ deg, const int* __restrict__ bsum,
                int* __restrict__ offs, int n)
{
    __shared__ int sh[1024];
    const int tid = threadIdx.x;
    const int gid = blockIdx.x * 1024 + tid;
    const int v = (gid < n) ? deg[gid] : 0;
    sh[tid] = v;
    __syncthreads();
    for (int ofs = 1; ofs < 1024; ofs <<= 1) {
        const int add = (tid >= ofs) ? sh[tid - ofs] : 0;
        __syncthreads();
        sh[tid] += add;
        __syncthreads();
    }
    if (gid < n) offs[gid] = bsum[blockIdx.x] + sh[tid] - v;
}

__global__ __launch_bounds__(256)
void scatter_kernel(const int* __restrict__ ei, const int* __restrict__ offs,
                    int* __restrict__ cur, int* __restrict__ srcs)
{
    const int e = blockIdx.x * 256 + threadIdx.x;
    if (e >= NE) return;
    const int t = ei[NE + e];   // tgt
    const int s = ei[e];        // src
    const int pos = offs[t] + atomicAdd(&cur[t], 1);
    srcs[pos] = s;
}

// ---------------- per-node attention + aggregation (1 wave / node, online softmax) ----------------
// Phase layout per 16-edge chunk: lane = 4*j_local + h computes score(j,h).
// Aggregation layout: lane owns dims {2l,2l+1}, head hd = l>>4; scores pulled via shfl.
__global__ __launch_bounds__(256)
void attn_agg(const float* __restrict__ Qb, const float* __restrict__ Kb,
              const float* __restrict__ Vb, const int* __restrict__ offs,
              const int* __restrict__ srcs, float* __restrict__ AGG)
{
    const int lane = threadIdx.x & 63;
    const int t = blockIdx.x * 4 + (threadIdx.x >> 6);
    if (t >= N_NODES) return;
    const int off = offs[t];
    const int deg = offs[t + 1] - off;
    const int h  = lane & 3;
    const int jl = lane >> 2;
    const int hd = lane >> 4;
    const int d0 = lane * 2;

    float4 q[8];
    {
        const float4* qp = (const float4*)(Qb + (size_t)t * DIM + h * DH);
        #pragma unroll
        for (int i = 0; i < 8; ++i) q[i] = qp[i];
    }

    float mrun = -3.0e38f;
    float ssum = 0.f, acc0 = 0.f, acc1 = 0.f;

    for (int base = 0; base < deg; base += 16) {
        const int rem = deg - base;
        const int cnt = rem < 16 ? rem : 16;
        float sc = -3.0e38f;
        int s = 0;
        if (jl < cnt) {
            s = srcs[off + base + jl];
            const float4* kp = (const float4*)(Kb + (size_t)s * DIM + h * DH);
            float d = 0.f;
            #pragma unroll
            for (int i = 0; i < 8; ++i) {
                const float4 kv = kp[i];
                d = fmaf(q[i].x, kv.x, d); d = fmaf(q[i].y, kv.y, d);
                d = fmaf(q[i].z, kv.z, d); d = fmaf(q[i].w, kv.w, d);
            }
            sc = d * SCALEF;
        }
        // per-head chunk max (lanes with equal h differ in bits 2..5)
        float cm = sc;
        #pragma unroll
        for (int w = 4; w < 64; w <<= 1) cm = fmaxf(cm, __shfl_xor(cm, w));
        const float cmh = __shfl(cm, hd);          // lane hd holds head-hd max
        const float newm = fmaxf(mrun, cmh);
        const float rescale = __expf(mrun - newm); // first chunk: exp(-inf) = 0
        ssum *= rescale; acc0 *= rescale; acc1 *= rescale;
        mrun = newm;

        #pragma unroll 4
        for (int jj = 0; jj < cnt; ++jj) {
            const float scj = __shfl(sc, jj * 4 + hd);
            const int   sj  = __shfl(s,  jj * 4);
            const float e   = __expf(scj - mrun);
            const float2 v  = *(const float2*)(Vb + (size_t)sj * DIM + d0);
            ssum += e;
            acc0 = fmaf(e, v.x, acc0);
            acc1 = fmaf(e, v.y, acc1);
        }
    }
    const float inv = 1.0f / (ssum + 1e-10f);
    *(float2*)(AGG + (size_t)t * DIM + d0) = make_float2(acc0 * inv, acc1 * inv);
}

// ---------------- rowwise LayerNorm ----------------
__global__ __launch_bounds__(256)
void ln_kernel(const float* __restrict__ Y, const float* __restrict__ g,
               const float* __restrict__ b, float* __restrict__ out)
{
    const int lane = threadIdx.x & 63;
    const int r = blockIdx.x * 4 + (threadIdx.x >> 6);
    if (r >= N_NODES) return;
    const float2 y2 = *(const float2*)(Y + (size_t)r * DIM + lane * 2);
    float s  = y2.x + y2.y;
    float sq = y2.x * y2.x + y2.y * y2.y;
    #pragma unroll
    for (int w = 1; w < 64; w <<= 1) { s += __shfl_xor(s, w); sq += __shfl_xor(sq, w); }
    const float mu   = s * (1.0f / 128.0f);
    const float var  = sq * (1.0f / 128.0f) - mu * mu;
    const float rstd = rsqrtf(var + 1e-5f);
    const float2 gv = *(const float2*)(g + lane * 2);
    const float2 bv = *(const float2*)(b + lane * 2);
    float2 o;
    o.x = gv.x * (y2.x - mu) * rstd + bv.x;
    o.y = gv.y * (y2.y - mu) * rstd + bv.y;
    *(float2*)(out + (size_t)r * DIM + lane * 2) = o;
}

extern "C" void kernel_launch(void* const* d_in, const int* in_sizes, int n_in,
                              void* d_out, int out_size, void* d_ws, size_t ws_size,
                              hipStream_t stream)
{
    const float* X   = (const float*)d_in[0];
    const float* Wq  = (const float*)d_in[1];
    const float* bq  = (const float*)d_in[2];
    const float* Wk  = (const float*)d_in[3];
    const float* bk  = (const float*)d_in[4];
    const float* Wv  = (const float*)d_in[5];
    const float* bv  = (const float*)d_in[6];
    const float* Wo  = (const float*)d_in[7];
    const float* bo  = (const float*)d_in[8];
    const float* lng = (const float*)d_in[9];
    const float* lnb = (const float*)d_in[10];
    const int*   ei  = (const int*)d_in[11];
    float* out = (float*)d_out;

    const size_t ND = (size_t)N_NODES * DIM;
    float* Qb  = (float*)d_ws;
    float* Kb  = Qb + ND;
    float* Vb  = Kb + ND;
    float* AGG = Vb + ND;
    float* Yb  = Qb;                       // reuse Q buffer after attention
    int* DEG   = (int*)(AGG + ND);
    int* OFFS  = DEG + N_NODES;
    int* CUR   = OFFS + N_NODES + 1;
    int* SRCS  = CUR + N_NODES;
    int* BSUM  = SRCS + NE;

    const int NB = (N_NODES + 1023) / 1024;   // 49

    hipMemsetAsync(DEG, 0, N_NODES * sizeof(int), stream);
    hipMemsetAsync(CUR, 0, N_NODES * sizeof(int), stream);

    const int gemmGrid = (N_NODES + 127) / 128;   // 391
    gemm_nt_128<false><<<gemmGrid, 256, 0, stream>>>(X, Wq, bq, nullptr, Qb, N_NODES);
    gemm_nt_128<false><<<gemmGrid, 256, 0, stream>>>(X, Wk, bk, nullptr, Kb, N_NODES);
    gemm_nt_128<false><<<gemmGrid, 256, 0, stream>>>(X, Wv, bv, nullptr, Vb, N_NODES);

    hist_kernel<<<NE / 256, 256, 0, stream>>>(ei + NE, DEG);
    block_sums<<<NB, 256, 0, stream>>>(DEG, BSUM, N_NODES);
    scan_bsum<<<1, 64, 0, stream>>>(BSUM, OFFS + N_NODES, NB);
    block_scan<<<NB, 1024, 0, stream>>>(DEG, BSUM, OFFS, N_NODES);
    scatter_kernel<<<NE / 256, 256, 0, stream>>>(ei, OFFS, CUR, SRCS);

    attn_agg<<<(N_NODES + 3) / 4, 256, 0, stream>>>(Qb, Kb, Vb, OFFS, SRCS, AGG);

    gemm_nt_128<true><<<gemmGrid, 256, 0, stream>>>(AGG, Wo, bo, X, Yb, N_NODES);
    ln_kernel<<<(N_NODES + 3) / 4, 256, 0, stream>>>(Yb, lng, lnb, out);
}

// Round 2
// 273.119 us; speedup vs baseline: 1.4910x; 1.4910x over previous
//
#include <hip/hip_runtime.h>

#define N_NODES 50000
#define DIM 128
#define NH 4
#define DH 32
#define NE 800000
#define SCALEF 0.17677669529663688f   // 1/sqrt(32)

typedef __attribute__((ext_vector_type(8))) short short8;     // 8 bf16 (4 VGPRs)
typedef __attribute__((ext_vector_type(4))) float f32x4;
typedef unsigned short u16;
typedef unsigned int u32;

__device__ __forceinline__ float b2f(u16 u) {
    union { u32 i; float f; } c; c.i = ((u32)u) << 16; return c.f;
}
__device__ __forceinline__ u16 f2b(float f) {   // round-to-nearest-even on raw bits
    union { float f; u32 i; } c; c.f = f;
    return (u16)((c.i + 0x7FFFu + ((c.i >> 16) & 1u)) >> 16);
}

// ---------------- fp32 -> bf16 convert (8 elems/thread), n % 8 == 0 ----------------
__global__ __launch_bounds__(256)
void f2b_kernel(const float* __restrict__ src, u16* __restrict__ dst, int n)
{
    const int i = (blockIdx.x * 256 + threadIdx.x) * 8;
    if (i >= n) return;
    const float4 a = *(const float4*)(src + i);
    const float4 b = *(const float4*)(src + i + 4);
    union { u16 us[8]; short8 v; } o;
    o.us[0] = f2b(a.x); o.us[1] = f2b(a.y); o.us[2] = f2b(a.z); o.us[3] = f2b(a.w);
    o.us[4] = f2b(b.x); o.us[5] = f2b(b.y); o.us[6] = f2b(b.z); o.us[7] = f2b(b.w);
    *(short8*)(dst + i) = o.v;
}

// ---------------- fused QKV projection: MFMA, K=128 in regs, no LDS ----------------
// C = A @ W^T + bias, outputs bf16. Wave = 32 rows x 128 cols.
__global__ __launch_bounds__(256)
void qkv_mfma(const u16* __restrict__ Xb,
              const u16* __restrict__ Wq, const u16* __restrict__ Wk, const u16* __restrict__ Wv,
              const float* __restrict__ bq, const float* __restrict__ bk, const float* __restrict__ bv,
              u16* __restrict__ Qo, u16* __restrict__ Ko, u16* __restrict__ Vo)
{
    const int lane = threadIdx.x & 63;
    const int wv   = threadIdx.x >> 6;
    const int m0   = blockIdx.x * 128 + wv * 32;
    const int rl   = lane & 15;
    const int kg   = lane >> 4;

    short8 a[2][4];
    #pragma unroll
    for (int rg = 0; rg < 2; ++rg) {
        const int row = m0 + rg * 16 + rl;
        #pragma unroll
        for (int ks = 0; ks < 4; ++ks) {
            if (row < N_NODES)
                a[rg][ks] = *(const short8*)(Xb + (size_t)row * DIM + ks * 32 + kg * 8);
            else
                a[rg][ks] = (short8)0;
        }
    }

    const u16*  Ws[3] = {Wq, Wk, Wv};
    const float* Bs[3] = {bq, bk, bv};
    u16*        Os[3] = {Qo, Ko, Vo};

    #pragma unroll
    for (int o = 0; o < 3; ++o) {
        const u16* W = Ws[o];
        u16* O = Os[o];
        #pragma unroll
        for (int ct = 0; ct < 8; ++ct) {
            const int c = ct * 16 + rl;                 // output col for this lane
            f32x4 acc0 = {0.f, 0.f, 0.f, 0.f};
            f32x4 acc1 = {0.f, 0.f, 0.f, 0.f};
            #pragma unroll
            for (int ks = 0; ks < 4; ++ks) {
                // B[k][c] = W[c][k], k = ks*32 + kg*8 + i  -> contiguous 16B from W row c
                const short8 b = *(const short8*)(W + (size_t)c * DIM + ks * 32 + kg * 8);
                acc0 = __builtin_amdgcn_mfma_f32_16x16x32_bf16(a[0][ks], b, acc0, 0, 0, 0);
                acc1 = __builtin_amdgcn_mfma_f32_16x16x32_bf16(a[1][ks], b, acc1, 0, 0, 0);
            }
            const float bias = Bs[o][c];
            #pragma unroll
            for (int j = 0; j < 4; ++j) {
                const int r0 = m0 + kg * 4 + j;         // rg=0 rows
                const int r1 = r0 + 16;                 // rg=1 rows
                if (r0 < N_NODES) O[(size_t)r0 * DIM + c] = f2b(acc0[j] + bias);
                if (r1 < N_NODES) O[(size_t)r1 * DIM + c] = f2b(acc1[j] + bias);
            }
        }
    }
}

// ---------------- output GEMM + bias + residual + LayerNorm, fused ----------------
__global__ __launch_bounds__(256)
void out_mfma_ln(const u16* __restrict__ Ab, const u16* __restrict__ Wo,
                 const float* __restrict__ bo, const float* __restrict__ X,
                 const float* __restrict__ lng, const float* __restrict__ lnb,
                 float* __restrict__ out)
{
    const int lane = threadIdx.x & 63;
    const int wv   = threadIdx.x >> 6;
    const int m0   = blockIdx.x * 128 + wv * 32;
    const int rl   = lane & 15;
    const int kg   = lane >> 4;

    short8 a[2][4];
    #pragma unroll
    for (int rg = 0; rg < 2; ++rg) {
        const int row = m0 + rg * 16 + rl;
        #pragma unroll
        for (int ks = 0; ks < 4; ++ks) {
            if (row < N_NODES)
                a[rg][ks] = *(const short8*)(Ab + (size_t)row * DIM + ks * 32 + kg * 8);
            else
                a[rg][ks] = (short8)0;
        }
    }

    float y[2][8][4];
    #pragma unroll
    for (int ct = 0; ct < 8; ++ct) {
        const int c = ct * 16 + rl;
        f32x4 acc0 = {0.f, 0.f, 0.f, 0.f};
        f32x4 acc1 = {0.f, 0.f, 0.f, 0.f};
        #pragma unroll
        for (int ks = 0; ks < 4; ++ks) {
            const short8 b = *(const short8*)(Wo + (size_t)c * DIM + ks * 32 + kg * 8);
            acc0 = __builtin_amdgcn_mfma_f32_16x16x32_bf16(a[0][ks], b, acc0, 0, 0, 0);
            acc1 = __builtin_amdgcn_mfma_f32_16x16x32_bf16(a[1][ks], b, acc1, 0, 0, 0);
        }
        const float bias = bo[c];
        #pragma unroll
        for (int j = 0; j < 4; ++j) {
            const int r0 = m0 + kg * 4 + j;
            const int r1 = r0 + 16;
            const float x0 = (r0 < N_NODES) ? X[(size_t)r0 * DIM + c] : 0.f;
            const float x1 = (r1 < N_NODES) ? X[(size_t)r1 * DIM + c] : 0.f;
            y[0][ct][j] = acc0[j] + bias + x0;
            y[1][ct][j] = acc1[j] + bias + x1;
        }
    }

    // LayerNorm: row r's 128 cols live in the 16 lanes sharing (lane>>4)
    #pragma unroll
    for (int rg = 0; rg < 2; ++rg) {
        #pragma unroll
        for (int j = 0; j < 4; ++j) {
            float s = 0.f, sq = 0.f;
            #pragma unroll
            for (int ct = 0; ct < 8; ++ct) { const float v = y[rg][ct][j]; s += v; sq += v * v; }
            #pragma unroll
            for (int w = 1; w < 16; w <<= 1) { s += __shfl_xor(s, w); sq += __shfl_xor(sq, w); }
            const float mu   = s * (1.0f / 128.0f);
            const float var  = sq * (1.0f / 128.0f) - mu * mu;
            const float rstd = rsqrtf(var + 1e-5f);
            const int r = m0 + rg * 16 + kg * 4 + j;
            if (r < N_NODES) {
                #pragma unroll
                for (int ct = 0; ct < 8; ++ct) {
                    const int c = ct * 16 + rl;
                    out[(size_t)r * DIM + c] = lng[c] * (y[rg][ct][j] - mu) * rstd + lnb[c];
                }
            }
        }
    }
}

// ---------------- CSR build: histogram -> scan -> scatter ----------------
__global__ __launch_bounds__(256)
void hist_kernel(const int* __restrict__ tgt, int* __restrict__ deg)
{
    const int e = blockIdx.x * 256 + threadIdx.x;
    if (e < NE) atomicAdd(&deg[tgt[e]], 1);
}

__global__ __launch_bounds__(256)
void block_sums(const int* __restrict__ deg, int* __restrict__ bsum, int n)
{
    __shared__ int acc4[4];
    const int b0 = blockIdx.x * 1024;
    int sum = 0;
    for (int i = threadIdx.x; i < 1024; i += 256) {
        const int g = b0 + i;
        sum += (g < n) ? deg[g] : 0;
    }
    #pragma unroll
    for (int w = 1; w < 64; w <<= 1) sum += __shfl_xor(sum, w);
    if ((threadIdx.x & 63) == 0) acc4[threadIdx.x >> 6] = sum;
    __syncthreads();
    if (threadIdx.x == 0) bsum[blockIdx.x] = acc4[0] + acc4[1] + acc4[2] + acc4[3];
}

__global__ void scan_bsum(int* __restrict__ bsum, int* __restrict__ offs_end, int nb)
{
    const int lane = threadIdx.x;           // 64 threads, 1 block
    const int v = (lane < nb) ? bsum[lane] : 0;
    int incl = v;
    #pragma unroll
    for (int w = 1; w < 64; w <<= 1) {
        const int t = __shfl_up(incl, w);
        if (lane >= w) incl += t;
    }
    if (lane < nb) bsum[lane] = incl - v;   // exclusive
    if (lane == 63) offs_end[0] = incl;     // total == NE
}

__global__ __launch_bounds__(1024)
void block_scan(const int* __restrict__ deg, const int* __restrict__ bsum,
                int* __restrict__ offs, int n)
{
    __shared__ int sh[1024];
    const int tid = threadIdx.x;
    const int gid = blockIdx.x * 1024 + tid;
    const int v = (gid < n) ? deg[gid] : 0;
    sh[tid] = v;
    __syncthreads();
    for (int ofs = 1; ofs < 1024; ofs <<= 1) {
        const int add = (tid >= ofs) ? sh[tid - ofs] : 0;
        __syncthreads();
        sh[tid] += add;
        __syncthreads();
    }
    if (gid < n) offs[gid] = bsum[blockIdx.x] + sh[tid] - v;
}

__global__ __launch_bounds__(256)
void scatter_kernel(const int* __restrict__ ei, const int* __restrict__ offs,
                    int* __restrict__ cur, int* __restrict__ srcs)
{
    const int e = blockIdx.x * 256 + threadIdx.x;
    if (e >= NE) return;
    const int t = ei[NE + e];   // tgt
    const int s = ei[e];        // src
    const int pos = offs[t] + atomicAdd(&cur[t], 1);
    srcs[pos] = s;
}

// ---------------- per-node attention + aggregation (1 wave / node, bf16 gathers) ----------------
__global__ __launch_bounds__(256)
void attn_agg(const u16* __restrict__ Qb, const u16* __restrict__ Kb,
              const u16* __restrict__ Vb, const int* __restrict__ offs,
              const int* __restrict__ srcs, u16* __restrict__ AGG)
{
    const int lane = threadIdx.x & 63;
    const int t = blockIdx.x * 4 + (threadIdx.x >> 6);
    if (t >= N_NODES) return;
    const int off = offs[t];
    const int deg = offs[t + 1] - off;
    const int h  = lane & 3;
    const int jl = lane >> 2;
    const int hd = lane >> 4;
    const int d0 = lane * 2;

    float q[32];
    {
        const u16* qp = Qb + (size_t)t * DIM + h * DH;
        #pragma unroll
        for (int i = 0; i < 4; ++i) {
            union { short8 v; u16 us[8]; } c;
            c.v = *(const short8*)(qp + i * 8);
            #pragma unroll
            for (int e = 0; e < 8; ++e) q[i * 8 + e] = b2f(c.us[e]);
        }
    }

    float mrun = -3.0e38f;
    float ssum = 0.f, acc0 = 0.f, acc1 = 0.f;

    for (int base = 0; base < deg; base += 16) {
        const int rem = deg - base;
        const int cnt = rem < 16 ? rem : 16;
        float sc = -3.0e38f;
        int s = 0;
        if (jl < cnt) {
            s = srcs[off + base + jl];
            const u16* kp = Kb + (size_t)s * DIM + h * DH;
            float d = 0.f;
            #pragma unroll
            for (int i = 0; i < 4; ++i) {
                union { short8 v; u16 us[8]; } c;
                c.v = *(const short8*)(kp + i * 8);
                #pragma unroll
                for (int e = 0; e < 8; ++e) d = fmaf(q[i * 8 + e], b2f(c.us[e]), d);
            }
            sc = d * SCALEF;
        }
        // per-head chunk max (lanes with equal h differ in bits 2..5)
        float cm = sc;
        #pragma unroll
        for (int w = 4; w < 64; w <<= 1) cm = fmaxf(cm, __shfl_xor(cm, w));
        const float cmh = __shfl(cm, hd);
        const float newm = fmaxf(mrun, cmh);
        const float rescale = __expf(mrun - newm);
        ssum *= rescale; acc0 *= rescale; acc1 *= rescale;
        mrun = newm;

        #pragma unroll 4
        for (int jj = 0; jj < cnt; ++jj) {
            const float scj = __shfl(sc, jj * 4 + hd);
            const int   sj  = __shfl(s,  jj * 4);
            const float e   = __expf(scj - mrun);
            const u32 vv = *(const u32*)(Vb + (size_t)sj * DIM + d0);
            union { u32 i; float f; } v0, v1;
            v0.i = vv << 16;
            v1.i = vv & 0xFFFF0000u;
            ssum += e;
            acc0 = fmaf(e, v0.f, acc0);
            acc1 = fmaf(e, v1.f, acc1);
        }
    }
    const float inv = 1.0f / (ssum + 1e-10f);
    const u32 packed = (u32)f2b(acc0 * inv) | ((u32)f2b(acc1 * inv) << 16);
    *(u32*)(AGG + (size_t)t * DIM + d0) = packed;
}

extern "C" void kernel_launch(void* const* d_in, const int* in_sizes, int n_in,
                              void* d_out, int out_size, void* d_ws, size_t ws_size,
                              hipStream_t stream)
{
    const float* X   = (const float*)d_in[0];
    const float* Wq  = (const float*)d_in[1];
    const float* bq  = (const float*)d_in[2];
    const float* Wk  = (const float*)d_in[3];
    const float* bk  = (const float*)d_in[4];
    const float* Wv  = (const float*)d_in[5];
    const float* bv  = (const float*)d_in[6];
    const float* Wo  = (const float*)d_in[7];
    const float* bo  = (const float*)d_in[8];
    const float* lng = (const float*)d_in[9];
    const float* lnb = (const float*)d_in[10];
    const int*   ei  = (const int*)d_in[11];
    float* out = (float*)d_out;

    const size_t ND = (size_t)N_NODES * DIM;   // 6.4M elems
    u16* Xb   = (u16*)d_ws;
    u16* Qb   = Xb + ND;
    u16* Kb   = Qb + ND;
    u16* Vb   = Kb + ND;
    u16* AGGb = Vb + ND;
    u16* Wqb  = AGGb + ND;
    u16* Wkb  = Wqb + DIM * DIM;
    u16* Wvb  = Wkb + DIM * DIM;
    u16* Wob  = Wvb + DIM * DIM;
    int* DEG  = (int*)(Wob + DIM * DIM);
    int* OFFS = DEG + N_NODES;
    int* CUR  = OFFS + N_NODES + 1;
    int* SRCS = CUR + N_NODES;
    int* BSUM = SRCS + NE;

    const int NB = (N_NODES + 1023) / 1024;   // 49

    hipMemsetAsync(DEG, 0, N_NODES * sizeof(int), stream);
    hipMemsetAsync(CUR, 0, N_NODES * sizeof(int), stream);

    // bf16 conversions
    f2b_kernel<<<(int)(ND / 8 + 255) / 256, 256, 0, stream>>>(X, Xb, (int)ND);
    f2b_kernel<<<8, 256, 0, stream>>>(Wq, Wqb, DIM * DIM);
    f2b_kernel<<<8, 256, 0, stream>>>(Wk, Wkb, DIM * DIM);
    f2b_kernel<<<8, 256, 0, stream>>>(Wv, Wvb, DIM * DIM);
    f2b_kernel<<<8, 256, 0, stream>>>(Wo, Wob, DIM * DIM);

    // CSR build
    hist_kernel<<<NE / 256, 256, 0, stream>>>(ei + NE, DEG);
    block_sums<<<NB, 256, 0, stream>>>(DEG, BSUM, N_NODES);
    scan_bsum<<<1, 64, 0, stream>>>(BSUM, OFFS + N_NODES, NB);
    block_scan<<<NB, 1024, 0, stream>>>(DEG, BSUM, OFFS, N_NODES);
    scatter_kernel<<<NE / 256, 256, 0, stream>>>(ei, OFFS, CUR, SRCS);

    // projections
    const int gemmGrid = (N_NODES + 127) / 128;   // 391
    qkv_mfma<<<gemmGrid, 256, 0, stream>>>(Xb, Wqb, Wkb, Wvb, bq, bk, bv, Qb, Kb, Vb);

    // attention + aggregation
    attn_agg<<<(N_NODES + 3) / 4, 256, 0, stream>>>(Qb, Kb, Vb, OFFS, SRCS, AGGb);

    // output projection + residual + LayerNorm
    out_mfma_ln<<<gemmGrid, 256, 0, stream>>>(AGGb, Wob, bo, X, lng, lnb, out);
}

// Round 3
// 232.621 us; speedup vs baseline: 1.7505x; 1.1741x over previous
//
#include <hip/hip_runtime.h>

#define N_NODES 50000
#define DIM 128
#define NH 4
#define DH 32
#define NE 800000
#define SCALEF 0.17677669529663688f   // 1/sqrt(32)

typedef __attribute__((ext_vector_type(8))) short short8;     // 8 bf16 (4 VGPRs)
typedef __attribute__((ext_vector_type(4))) float f32x4;
typedef unsigned short u16;
typedef unsigned int u32;

__device__ __forceinline__ float b2f(u16 u) {
    union { u32 i; float f; } c; c.i = ((u32)u) << 16; return c.f;
}
__device__ __forceinline__ u16 f2b(float f) {   // round-to-nearest-even on raw bits
    union { float f; u32 i; } c; c.f = f;
    return (u16)((c.i + 0x7FFFu + ((c.i >> 16) & 1u)) >> 16);
}

// ---------------- fp32 -> bf16 for the 4 weight matrices (one launch) ----------------
__global__ __launch_bounds__(256)
void f2b_w(const float* __restrict__ w0, const float* __restrict__ w1,
           const float* __restrict__ w2, const float* __restrict__ w3,
           u16* __restrict__ o0, u16* __restrict__ o1,
           u16* __restrict__ o2, u16* __restrict__ o3)
{
    const float* src; u16* dst;
    switch (blockIdx.y) {
        case 0: src = w0; dst = o0; break;
        case 1: src = w1; dst = o1; break;
        case 2: src = w2; dst = o2; break;
        default: src = w3; dst = o3; break;
    }
    const int i = (blockIdx.x * 256 + threadIdx.x) * 8;   // 16384 elems per weight
    const float4 a = *(const float4*)(src + i);
    const float4 b = *(const float4*)(src + i + 4);
    union { u16 us[8]; short8 v; } o;
    o.us[0] = f2b(a.x); o.us[1] = f2b(a.y); o.us[2] = f2b(a.z); o.us[3] = f2b(a.w);
    o.us[4] = f2b(b.x); o.us[5] = f2b(b.y); o.us[6] = f2b(b.z); o.us[7] = f2b(b.w);
    *(short8*)(dst + i) = o.v;
}

// ---------------- fused QKV projection: MFMA, K=128 in regs, fp32 X converted inline ----------------
__global__ __launch_bounds__(256)
void qkv_mfma(const float* __restrict__ X,
              const u16* __restrict__ Wq, const u16* __restrict__ Wk, const u16* __restrict__ Wv,
              const float* __restrict__ bq, const float* __restrict__ bk, const float* __restrict__ bv,
              u16* __restrict__ Qo, u16* __restrict__ Ko, u16* __restrict__ Vo)
{
    const int lane = threadIdx.x & 63;
    const int wv   = threadIdx.x >> 6;
    const int m0   = blockIdx.x * 128 + wv * 32;
    const int rl   = lane & 15;
    const int kg   = lane >> 4;

    short8 a[2][4];
    #pragma unroll
    for (int rg = 0; rg < 2; ++rg) {
        const int row = m0 + rg * 16 + rl;
        #pragma unroll
        for (int ks = 0; ks < 4; ++ks) {
            if (row < N_NODES) {
                const float* xp = X + (size_t)row * DIM + ks * 32 + kg * 8;
                const float4 x0 = *(const float4*)(xp);
                const float4 x1 = *(const float4*)(xp + 4);
                union { u16 us[8]; short8 v; } c;
                c.us[0] = f2b(x0.x); c.us[1] = f2b(x0.y); c.us[2] = f2b(x0.z); c.us[3] = f2b(x0.w);
                c.us[4] = f2b(x1.x); c.us[5] = f2b(x1.y); c.us[6] = f2b(x1.z); c.us[7] = f2b(x1.w);
                a[rg][ks] = c.v;
            } else {
                a[rg][ks] = (short8)0;
            }
        }
    }

    const u16*  Ws[3] = {Wq, Wk, Wv};
    const float* Bs[3] = {bq, bk, bv};
    u16*        Os[3] = {Qo, Ko, Vo};

    #pragma unroll
    for (int o = 0; o < 3; ++o) {
        const u16* W = Ws[o];
        u16* O = Os[o];
        #pragma unroll
        for (int ct = 0; ct < 8; ++ct) {
            const int c = ct * 16 + rl;                 // output col for this lane
            f32x4 acc0 = {0.f, 0.f, 0.f, 0.f};
            f32x4 acc1 = {0.f, 0.f, 0.f, 0.f};
            #pragma unroll
            for (int ks = 0; ks < 4; ++ks) {
                const short8 b = *(const short8*)(W + (size_t)c * DIM + ks * 32 + kg * 8);
                acc0 = __builtin_amdgcn_mfma_f32_16x16x32_bf16(a[0][ks], b, acc0, 0, 0, 0);
                acc1 = __builtin_amdgcn_mfma_f32_16x16x32_bf16(a[1][ks], b, acc1, 0, 0, 0);
            }
            const float bias = Bs[o][c];
            #pragma unroll
            for (int j = 0; j < 4; ++j) {
                const int r0 = m0 + kg * 4 + j;         // rg=0 rows
                const int r1 = r0 + 16;                 // rg=1 rows
                if (r0 < N_NODES) O[(size_t)r0 * DIM + c] = f2b(acc0[j] + bias);
                if (r1 < N_NODES) O[(size_t)r1 * DIM + c] = f2b(acc1[j] + bias);
            }
        }
    }
}

// ---------------- output GEMM + bias + residual + LayerNorm, fused ----------------
__global__ __launch_bounds__(256)
void out_mfma_ln(const u16* __restrict__ Ab, const u16* __restrict__ Wo,
                 const float* __restrict__ bo, const float* __restrict__ X,
                 const float* __restrict__ lng, const float* __restrict__ lnb,
                 float* __restrict__ out)
{
    const int lane = threadIdx.x & 63;
    const int wv   = threadIdx.x >> 6;
    const int m0   = blockIdx.x * 128 + wv * 32;
    const int rl   = lane & 15;
    const int kg   = lane >> 4;

    short8 a[2][4];
    #pragma unroll
    for (int rg = 0; rg < 2; ++rg) {
        const int row = m0 + rg * 16 + rl;
        #pragma unroll
        for (int ks = 0; ks < 4; ++ks) {
            if (row < N_NODES)
                a[rg][ks] = *(const short8*)(Ab + (size_t)row * DIM + ks * 32 + kg * 8);
            else
                a[rg][ks] = (short8)0;
        }
    }

    float y[2][8][4];
    #pragma unroll
    for (int ct = 0; ct < 8; ++ct) {
        const int c = ct * 16 + rl;
        f32x4 acc0 = {0.f, 0.f, 0.f, 0.f};
        f32x4 acc1 = {0.f, 0.f, 0.f, 0.f};
        #pragma unroll
        for (int ks = 0; ks < 4; ++ks) {
            const short8 b = *(const short8*)(Wo + (size_t)c * DIM + ks * 32 + kg * 8);
            acc0 = __builtin_amdgcn_mfma_f32_16x16x32_bf16(a[0][ks], b, acc0, 0, 0, 0);
            acc1 = __builtin_amdgcn_mfma_f32_16x16x32_bf16(a[1][ks], b, acc1, 0, 0, 0);
        }
        const float bias = bo[c];
        #pragma unroll
        for (int j = 0; j < 4; ++j) {
            const int r0 = m0 + kg * 4 + j;
            const int r1 = r0 + 16;
            const float x0 = (r0 < N_NODES) ? X[(size_t)r0 * DIM + c] : 0.f;
            const float x1 = (r1 < N_NODES) ? X[(size_t)r1 * DIM + c] : 0.f;
            y[0][ct][j] = acc0[j] + bias + x0;
            y[1][ct][j] = acc1[j] + bias + x1;
        }
    }

    // LayerNorm: row r's 128 cols live in the 16 lanes sharing (lane>>4)
    #pragma unroll
    for (int rg = 0; rg < 2; ++rg) {
        #pragma unroll
        for (int j = 0; j < 4; ++j) {
            float s = 0.f, sq = 0.f;
            #pragma unroll
            for (int ct = 0; ct < 8; ++ct) { const float v = y[rg][ct][j]; s += v; sq += v * v; }
            #pragma unroll
            for (int w = 1; w < 16; w <<= 1) { s += __shfl_xor(s, w); sq += __shfl_xor(sq, w); }
            const float mu   = s * (1.0f / 128.0f);
            const float var  = sq * (1.0f / 128.0f) - mu * mu;
            const float rstd = rsqrtf(var + 1e-5f);
            const int r = m0 + rg * 16 + kg * 4 + j;
            if (r < N_NODES) {
                #pragma unroll
                for (int ct = 0; ct < 8; ++ct) {
                    const int c = ct * 16 + rl;
                    out[(size_t)r * DIM + c] = lng[c] * (y[rg][ct][j] - mu) * rstd + lnb[c];
                }
            }
        }
    }
}

// ---------------- CSR build: histogram -> scan -> scatter ----------------
__global__ __launch_bounds__(256)
void hist_kernel(const int* __restrict__ tgt, int* __restrict__ deg)
{
    const int i = (blockIdx.x * 256 + threadIdx.x) * 4;
    if (i >= NE) return;
    const int4 t4 = *(const int4*)(tgt + i);
    atomicAdd(&deg[t4.x], 1); atomicAdd(&deg[t4.y], 1);
    atomicAdd(&deg[t4.z], 1); atomicAdd(&deg[t4.w], 1);
}

__global__ __launch_bounds__(256)
void block_sums(const int* __restrict__ deg, int* __restrict__ bsum, int n)
{
    __shared__ int acc4[4];
    const int b0 = blockIdx.x * 1024;
    int sum = 0;
    for (int i = threadIdx.x; i < 1024; i += 256) {
        const int g = b0 + i;
        sum += (g < n) ? deg[g] : 0;
    }
    #pragma unroll
    for (int w = 1; w < 64; w <<= 1) sum += __shfl_xor(sum, w);
    if ((threadIdx.x & 63) == 0) acc4[threadIdx.x >> 6] = sum;
    __syncthreads();
    if (threadIdx.x == 0) bsum[blockIdx.x] = acc4[0] + acc4[1] + acc4[2] + acc4[3];
}

__global__ void scan_bsum(int* __restrict__ bsum, int* __restrict__ offs_end, int nb)
{
    const int lane = threadIdx.x;           // 64 threads, 1 block
    const int v = (lane < nb) ? bsum[lane] : 0;
    int incl = v;
    #pragma unroll
    for (int w = 1; w < 64; w <<= 1) {
        const int t = __shfl_up(incl, w);
        if (lane >= w) incl += t;
    }
    if (lane < nb) bsum[lane] = incl - v;   // exclusive
    if (lane == 63) offs_end[0] = incl;     // total == NE
}

__global__ __launch_bounds__(1024)
void block_scan(const int* __restrict__ deg, const int* __restrict__ bsum,
                int* __restrict__ offs, int n)
{
    __shared__ int sh[1024];
    const int tid = threadIdx.x;
    const int gid = blockIdx.x * 1024 + tid;
    const int v = (gid < n) ? deg[gid] : 0;
    sh[tid] = v;
    __syncthreads();
    for (int ofs = 1; ofs < 1024; ofs <<= 1) {
        const int add = (tid >= ofs) ? sh[tid - ofs] : 0;
        __syncthreads();
        sh[tid] += add;
        __syncthreads();
    }
    if (gid < n) offs[gid] = bsum[blockIdx.x] + sh[tid] - v;
}

__global__ __launch_bounds__(256)
void scatter_kernel(const int* __restrict__ ei, const int* __restrict__ offs,
                    int* __restrict__ cur, int* __restrict__ srcs)
{
    const int i = (blockIdx.x * 256 + threadIdx.x) * 4;
    if (i >= NE) return;
    const int4 t4 = *(const int4*)(ei + NE + i);
    const int4 s4 = *(const int4*)(ei + i);
    int pos;
    pos = offs[t4.x] + atomicAdd(&cur[t4.x], 1); srcs[pos] = s4.x;
    pos = offs[t4.y] + atomicAdd(&cur[t4.y], 1); srcs[pos] = s4.y;
    pos = offs[t4.z] + atomicAdd(&cur[t4.z], 1); srcs[pos] = s4.z;
    pos = offs[t4.w] + atomicAdd(&cur[t4.w], 1); srcs[pos] = s4.w;
}

// ---------------- per-node attention + aggregation ----------------
// 1 wave / node. No max-subtraction (scores ~N(0,1), exp safe in fp32; softmax invariant).
// Score layout: lane = 4*jl + h. Aggregate layout: lane owns dims {2l,2l+1}, head hd=l>>4.
// All 16 V-row loads of a chunk issued back-to-back; next chunk's srcs+K prefetched.
__global__ __launch_bounds__(256)
void attn_agg(const u16* __restrict__ Qb, const u16* __restrict__ Kb,
              const u16* __restrict__ Vb, const int* __restrict__ offs,
              const int* __restrict__ srcs, u16* __restrict__ AGG)
{
    const int lane = threadIdx.x & 63;
    const int t = blockIdx.x * 4 + (threadIdx.x >> 6);
    if (t >= N_NODES) return;
    const int off = offs[t];
    const int deg = offs[t + 1] - off;
    const int h  = lane & 3;
    const int jl = lane >> 2;
    const int hd = lane >> 4;
    const int d0 = lane * 2;

    float q[32];
    {
        const u16* qp = Qb + (size_t)t * DIM + h * DH;
        #pragma unroll
        for (int i = 0; i < 4; ++i) {
            union { short8 v; u16 us[8]; } c;
            c.v = *(const short8*)(qp + i * 8);
            #pragma unroll
            for (int e = 0; e < 8; ++e) q[i * 8 + e] = b2f(c.us[e]);
        }
    }

    float ssum = 0.f, acc0 = 0.f, acc1 = 0.f;
    const int nch = (deg + 15) >> 4;

    int sA = 0;
    short8 kA[4] = {};
    {
        const int cnt0 = deg < 16 ? deg : 16;
        if (jl < cnt0) {
            sA = srcs[off + jl];
            const u16* kp = Kb + (size_t)sA * DIM + h * DH;
            kA[0] = *(const short8*)(kp);
            kA[1] = *(const short8*)(kp + 8);
            kA[2] = *(const short8*)(kp + 16);
            kA[3] = *(const short8*)(kp + 24);
        }
    }

    for (int c = 0; c < nch; ++c) {
        const int base = c << 4;
        const int cnt = (deg - base) < 16 ? (deg - base) : 16;

        // prefetch next chunk
        int sB = 0;
        short8 kB[4] = {};
        if (c + 1 < nch) {
            const int rem = deg - base - 16;
            const int cntn = rem < 16 ? rem : 16;
            if (jl < cntn) {
                sB = srcs[off + base + 16 + jl];
                const u16* kp = Kb + (size_t)sB * DIM + h * DH;
                kB[0] = *(const short8*)(kp);
                kB[1] = *(const short8*)(kp + 8);
                kB[2] = *(const short8*)(kp + 16);
                kB[3] = *(const short8*)(kp + 24);
            }
        }

        // score for this lane's (edge jl, head h)
        float dq = 0.f;
        #pragma unroll
        for (int i = 0; i < 4; ++i) {
            union { short8 v; u32 uu[4]; } cc;
            cc.v = kA[i];
            #pragma unroll
            for (int p = 0; p < 4; ++p) {
                union { u32 i; float f; } lo, hi;
                lo.i = cc.uu[p] << 16;
                hi.i = cc.uu[p] & 0xFFFF0000u;
                dq = fmaf(q[i * 8 + 2 * p],     lo.f, dq);
                dq = fmaf(q[i * 8 + 2 * p + 1], hi.f, dq);
            }
        }
        const float e = (jl < cnt) ? __expf(dq * SCALEF) : 0.f;

        // per-head sum of e (lanes sharing h differ in bits 2..5)
        float se = e;
        #pragma unroll
        for (int w = 4; w < 64; w <<= 1) se += __shfl_xor(se, w);
        ssum += __shfl(se, hd);

        // batched V gathers: 16 independent loads in flight
        u32 vv[16];
        #pragma unroll
        for (int jj = 0; jj < 16; ++jj) {
            const int sj = __shfl(sA, jj * 4);          // readlane broadcast
            vv[jj] = *(const u32*)(Vb + (size_t)sj * DIM + d0);
        }
        #pragma unroll
        for (int jj = 0; jj < 16; ++jj) {
            const float ejj = __shfl(e, jj * 4 + hd);
            union { u32 i; float f; } v0, v1;
            v0.i = vv[jj] << 16;
            v1.i = vv[jj] & 0xFFFF0000u;
            acc0 = fmaf(ejj, v0.f, acc0);
            acc1 = fmaf(ejj, v1.f, acc1);
        }

        sA = sB;
        #pragma unroll
        for (int i = 0; i < 4; ++i) kA[i] = kB[i];
    }

    const float inv = 1.0f / (ssum + 1e-10f);
    const u32 packed = (u32)f2b(acc0 * inv) | ((u32)f2b(acc1 * inv) << 16);
    *(u32*)(AGG + (size_t)t * DIM + d0) = packed;
}

extern "C" void kernel_launch(void* const* d_in, const int* in_sizes, int n_in,
                              void* d_out, int out_size, void* d_ws, size_t ws_size,
                              hipStream_t stream)
{
    const float* X   = (const float*)d_in[0];
    const float* Wq  = (const float*)d_in[1];
    const float* bq  = (const float*)d_in[2];
    const float* Wk  = (const float*)d_in[3];
    const float* bk  = (const float*)d_in[4];
    const float* Wv  = (const float*)d_in[5];
    const float* bv  = (const float*)d_in[6];
    const float* Wo  = (const float*)d_in[7];
    const float* bo  = (const float*)d_in[8];
    const float* lng = (const float*)d_in[9];
    const float* lnb = (const float*)d_in[10];
    const int*   ei  = (const int*)d_in[11];
    float* out = (float*)d_out;

    const size_t ND = (size_t)N_NODES * DIM;   // 6.4M elems
    u16* Qb   = (u16*)d_ws;
    u16* Kb   = Qb + ND;
    u16* Vb   = Kb + ND;
    u16* AGGb = Vb + ND;
    u16* Wqb  = AGGb + ND;
    u16* Wkb  = Wqb + DIM * DIM;
    u16* Wvb  = Wkb + DIM * DIM;
    u16* Wob  = Wvb + DIM * DIM;
    int* DEG  = (int*)(Wob + DIM * DIM);
    int* OFFS = DEG + N_NODES;
    int* CUR  = OFFS + N_NODES + 1;
    int* SRCS = CUR + N_NODES;
    int* BSUM = SRCS + NE;

    const int NB = (N_NODES + 1023) / 1024;   // 49

    hipMemsetAsync(DEG, 0, N_NODES * sizeof(int), stream);
    hipMemsetAsync(CUR, 0, N_NODES * sizeof(int), stream);

    // weights -> bf16 (one launch)
    f2b_w<<<dim3(8, 4), 256, 0, stream>>>(Wq, Wk, Wv, Wo, Wqb, Wkb, Wvb, Wob);

    // CSR build
    hist_kernel<<<(NE / 4 + 255) / 256, 256, 0, stream>>>(ei + NE, DEG);
    block_sums<<<NB, 256, 0, stream>>>(DEG, BSUM, N_NODES);
    scan_bsum<<<1, 64, 0, stream>>>(BSUM, OFFS + N_NODES, NB);
    block_scan<<<NB, 1024, 0, stream>>>(DEG, BSUM, OFFS, N_NODES);
    scatter_kernel<<<(NE / 4 + 255) / 256, 256, 0, stream>>>(ei, OFFS, CUR, SRCS);

    // projections (X converted to bf16 inline)
    const int gemmGrid = (N_NODES + 127) / 128;   // 391
    qkv_mfma<<<gemmGrid, 256, 0, stream>>>(X, Wqb, Wkb, Wvb, bq, bk, bv, Qb, Kb, Vb);

    // attention + aggregation
    attn_agg<<<(N_NODES + 3) / 4, 256, 0, stream>>>(Qb, Kb, Vb, OFFS, SRCS, AGGb);

    // output projection + residual + LayerNorm
    out_mfma_ln<<<gemmGrid, 256, 0, stream>>>(AGGb, Wob, bo, X, lng, lnb, out);
}

// Round 4
// 221.394 us; speedup vs baseline: 1.8393x; 1.0507x over previous
//
#include <hip/hip_runtime.h>

#define N_NODES 50000
#define DIM 128
#define NH 4
#define DH 32
#define NE 800000
#define SCALEF 0.17677669529663688f   // 1/sqrt(32)

typedef _Float16 half_t;
typedef __attribute__((ext_vector_type(2))) _Float16 half2_t;
typedef __attribute__((ext_vector_type(4))) _Float16 half4_t;
typedef __attribute__((ext_vector_type(8))) _Float16 half8_t;
typedef __attribute__((ext_vector_type(4))) float f32x4;
typedef unsigned short u16;
typedef unsigned int u32;

// ---------------- fp32 -> fp16 for the 4 weight matrices (one launch) ----------------
__global__ __launch_bounds__(256)
void f2h_w(const float* __restrict__ w0, const float* __restrict__ w1,
           const float* __restrict__ w2, const float* __restrict__ w3,
           half_t* __restrict__ o0, half_t* __restrict__ o1,
           half_t* __restrict__ o2, half_t* __restrict__ o3)
{
    const float* src; half_t* dst;
    switch (blockIdx.y) {
        case 0: src = w0; dst = o0; break;
        case 1: src = w1; dst = o1; break;
        case 2: src = w2; dst = o2; break;
        default: src = w3; dst = o3; break;
    }
    const int i = (blockIdx.x * 256 + threadIdx.x) * 8;   // 16384 elems per weight
    const float4 a = *(const float4*)(src + i);
    const float4 b = *(const float4*)(src + i + 4);
    half8_t o;
    o[0] = (_Float16)a.x; o[1] = (_Float16)a.y; o[2] = (_Float16)a.z; o[3] = (_Float16)a.w;
    o[4] = (_Float16)b.x; o[5] = (_Float16)b.y; o[6] = (_Float16)b.z; o[7] = (_Float16)b.w;
    *(half8_t*)(dst + i) = o;
}

// ---------------- fused QKV projection: MFMA f16, transposed output (D[outcol][node]) ----------
// A-frag = W rows (row=outcol), B-frag = X (col=node). Lane holds 4 consecutive outcols
// of one node per acc -> 8B stores. Wave covers 32 nodes (2 node-groups).
__global__ __launch_bounds__(256)
void qkv_mfma(const float* __restrict__ X,
              const half_t* __restrict__ Wq, const half_t* __restrict__ Wk, const half_t* __restrict__ Wv,
              const float* __restrict__ bq, const float* __restrict__ bk, const float* __restrict__ bv,
              half_t* __restrict__ Qo, half_t* __restrict__ Ko, half_t* __restrict__ Vo)
{
    const int lane = threadIdx.x & 63;
    const int wv   = threadIdx.x >> 6;
    const int m0   = blockIdx.x * 128 + wv * 32;
    const int cl   = lane & 15;           // node within group / W row within tile
    const int kg   = lane >> 4;           // k-slice

    half8_t bx[2][4];
    #pragma unroll
    for (int ng = 0; ng < 2; ++ng) {
        const int row = m0 + ng * 16 + cl;
        #pragma unroll
        for (int ks = 0; ks < 4; ++ks) {
            if (row < N_NODES) {
                const float* xp = X + (size_t)row * DIM + ks * 32 + kg * 8;
                const float4 x0 = *(const float4*)(xp);
                const float4 x1 = *(const float4*)(xp + 4);
                half8_t c;
                c[0] = (_Float16)x0.x; c[1] = (_Float16)x0.y; c[2] = (_Float16)x0.z; c[3] = (_Float16)x0.w;
                c[4] = (_Float16)x1.x; c[5] = (_Float16)x1.y; c[6] = (_Float16)x1.z; c[7] = (_Float16)x1.w;
                bx[ng][ks] = c;
            } else {
                bx[ng][ks] = (half8_t)(_Float16)0.0f;
            }
        }
    }

    const half_t* Ws[3] = {Wq, Wk, Wv};
    const float*  Bs[3] = {bq, bk, bv};
    half_t*       Os[3] = {Qo, Ko, Vo};

    #pragma unroll
    for (int o = 0; o < 3; ++o) {
        const half_t* W = Ws[o];
        half_t* O = Os[o];
        #pragma unroll
        for (int ct = 0; ct < 8; ++ct) {
            f32x4 acc0 = {0.f, 0.f, 0.f, 0.f};
            f32x4 acc1 = {0.f, 0.f, 0.f, 0.f};
            #pragma unroll
            for (int ks = 0; ks < 4; ++ks) {
                const half8_t a = *(const half8_t*)(W + (size_t)(ct * 16 + cl) * DIM + ks * 32 + kg * 8);
                acc0 = __builtin_amdgcn_mfma_f32_16x16x32_f16(a, bx[0][ks], acc0, 0, 0, 0);
                acc1 = __builtin_amdgcn_mfma_f32_16x16x32_f16(a, bx[1][ks], acc1, 0, 0, 0);
            }
            const int c0 = ct * 16 + kg * 4;            // this lane's 4 consecutive outcols
            const float4 b4 = *(const float4*)(Bs[o] + c0);
            const int n0 = m0 + cl;
            if (n0 < N_NODES) {
                half4_t hd4;
                hd4[0] = (_Float16)(acc0[0] + b4.x); hd4[1] = (_Float16)(acc0[1] + b4.y);
                hd4[2] = (_Float16)(acc0[2] + b4.z); hd4[3] = (_Float16)(acc0[3] + b4.w);
                *(half4_t*)(O + (size_t)n0 * DIM + c0) = hd4;
            }
            const int n1 = m0 + 16 + cl;
            if (n1 < N_NODES) {
                half4_t hd4;
                hd4[0] = (_Float16)(acc1[0] + b4.x); hd4[1] = (_Float16)(acc1[1] + b4.y);
                hd4[2] = (_Float16)(acc1[2] + b4.z); hd4[3] = (_Float16)(acc1[3] + b4.w);
                *(half4_t*)(O + (size_t)n1 * DIM + c0) = hd4;
            }
        }
    }
}

// ---------------- output GEMM + bias + residual + LayerNorm, transposed output ----------------
__global__ __launch_bounds__(256)
void out_mfma_ln(const half_t* __restrict__ Ah, const half_t* __restrict__ Wo,
                 const float* __restrict__ bo, const float* __restrict__ X,
                 const float* __restrict__ lng, const float* __restrict__ lnb,
                 float* __restrict__ out)
{
    const int lane = threadIdx.x & 63;
    const int wv   = threadIdx.x >> 6;
    const int m0   = blockIdx.x * 128 + wv * 32;
    const int cl   = lane & 15;
    const int kg   = lane >> 4;

    half8_t bx[2][4];
    #pragma unroll
    for (int ng = 0; ng < 2; ++ng) {
        const int row = m0 + ng * 16 + cl;
        #pragma unroll
        for (int ks = 0; ks < 4; ++ks) {
            if (row < N_NODES)
                bx[ng][ks] = *(const half8_t*)(Ah + (size_t)row * DIM + ks * 32 + kg * 8);
            else
                bx[ng][ks] = (half8_t)(_Float16)0.0f;
        }
    }

    float y[2][8][4];
    #pragma unroll
    for (int ct = 0; ct < 8; ++ct) {
        f32x4 acc0 = {0.f, 0.f, 0.f, 0.f};
        f32x4 acc1 = {0.f, 0.f, 0.f, 0.f};
        #pragma unroll
        for (int ks = 0; ks < 4; ++ks) {
            const half8_t a = *(const half8_t*)(Wo + (size_t)(ct * 16 + cl) * DIM + ks * 32 + kg * 8);
            acc0 = __builtin_amdgcn_mfma_f32_16x16x32_f16(a, bx[0][ks], acc0, 0, 0, 0);
            acc1 = __builtin_amdgcn_mfma_f32_16x16x32_f16(a, bx[1][ks], acc1, 0, 0, 0);
        }
        const int c0 = ct * 16 + kg * 4;
        const float4 b4 = *(const float4*)(bo + c0);
        const int n0 = m0 + cl;
        const int n1 = m0 + 16 + cl;
        float4 x0 = make_float4(0.f, 0.f, 0.f, 0.f), x1 = x0;
        if (n0 < N_NODES) x0 = *(const float4*)(X + (size_t)n0 * DIM + c0);
        if (n1 < N_NODES) x1 = *(const float4*)(X + (size_t)n1 * DIM + c0);
        y[0][ct][0] = acc0[0] + b4.x + x0.x; y[0][ct][1] = acc0[1] + b4.y + x0.y;
        y[0][ct][2] = acc0[2] + b4.z + x0.z; y[0][ct][3] = acc0[3] + b4.w + x0.w;
        y[1][ct][0] = acc1[0] + b4.x + x1.x; y[1][ct][1] = acc1[1] + b4.y + x1.y;
        y[1][ct][2] = acc1[2] + b4.z + x1.z; y[1][ct][3] = acc1[3] + b4.w + x1.w;
    }

    // LayerNorm: node (ng,cl)'s 128 cols live in the 4 lanes sharing cl (kg=0..3), 32 vals each
    #pragma unroll
    for (int ng = 0; ng < 2; ++ng) {
        float s = 0.f, sq = 0.f;
        #pragma unroll
        for (int ct = 0; ct < 8; ++ct)
            #pragma unroll
            for (int j = 0; j < 4; ++j) { const float v = y[ng][ct][j]; s += v; sq += v * v; }
        s += __shfl_xor(s, 16); sq += __shfl_xor(sq, 16);
        s += __shfl_xor(s, 32); sq += __shfl_xor(sq, 32);
        const float mu   = s * (1.0f / 128.0f);
        const float var  = sq * (1.0f / 128.0f) - mu * mu;
        const float rstd = rsqrtf(var + 1e-5f);
        const int node = m0 + ng * 16 + cl;
        if (node < N_NODES) {
            #pragma unroll
            for (int ct = 0; ct < 8; ++ct) {
                const int c0 = ct * 16 + kg * 4;
                const float4 g4 = *(const float4*)(lng + c0);
                const float4 l4 = *(const float4*)(lnb + c0);
                float4 ov;
                ov.x = g4.x * (y[ng][ct][0] - mu) * rstd + l4.x;
                ov.y = g4.y * (y[ng][ct][1] - mu) * rstd + l4.y;
                ov.z = g4.z * (y[ng][ct][2] - mu) * rstd + l4.z;
                ov.w = g4.w * (y[ng][ct][3] - mu) * rstd + l4.w;
                *(float4*)(out + (size_t)node * DIM + c0) = ov;
            }
        }
    }
}

// ---------------- CSR build: histogram -> scan -> scatter ----------------
__global__ __launch_bounds__(256)
void hist_kernel(const int* __restrict__ tgt, int* __restrict__ deg)
{
    const int i = (blockIdx.x * 256 + threadIdx.x) * 4;
    if (i >= NE) return;
    const int4 t4 = *(const int4*)(tgt + i);
    atomicAdd(&deg[t4.x], 1); atomicAdd(&deg[t4.y], 1);
    atomicAdd(&deg[t4.z], 1); atomicAdd(&deg[t4.w], 1);
}

__global__ __launch_bounds__(256)
void block_sums(const int* __restrict__ deg, int* __restrict__ bsum, int n)
{
    __shared__ int acc4[4];
    const int b0 = blockIdx.x * 1024;
    int sum = 0;
    for (int i = threadIdx.x; i < 1024; i += 256) {
        const int g = b0 + i;
        sum += (g < n) ? deg[g] : 0;
    }
    #pragma unroll
    for (int w = 1; w < 64; w <<= 1) sum += __shfl_xor(sum, w);
    if ((threadIdx.x & 63) == 0) acc4[threadIdx.x >> 6] = sum;
    __syncthreads();
    if (threadIdx.x == 0) bsum[blockIdx.x] = acc4[0] + acc4[1] + acc4[2] + acc4[3];
}

__global__ void scan_bsum(int* __restrict__ bsum, int* __restrict__ offs_end, int nb)
{
    const int lane = threadIdx.x;           // 64 threads, 1 block
    const int v = (lane < nb) ? bsum[lane] : 0;
    int incl = v;
    #pragma unroll
    for (int w = 1; w < 64; w <<= 1) {
        const int t = __shfl_up(incl, w);
        if (lane >= w) incl += t;
    }
    if (lane < nb) bsum[lane] = incl - v;   // exclusive
    if (lane == 63) offs_end[0] = incl;     // total == NE
}

__global__ __launch_bounds__(1024)
void block_scan(const int* __restrict__ deg, const int* __restrict__ bsum,
                int* __restrict__ offs, int n)
{
    __shared__ int sh[1024];
    const int tid = threadIdx.x;
    const int gid = blockIdx.x * 1024 + tid;
    const int v = (gid < n) ? deg[gid] : 0;
    sh[tid] = v;
    __syncthreads();
    for (int ofs = 1; ofs < 1024; ofs <<= 1) {
        const int add = (tid >= ofs) ? sh[tid - ofs] : 0;
        __syncthreads();
        sh[tid] += add;
        __syncthreads();
    }
    if (gid < n) offs[gid] = bsum[blockIdx.x] + sh[tid] - v;
}

__global__ __launch_bounds__(256)
void scatter_kernel(const int* __restrict__ ei, const int* __restrict__ offs,
                    int* __restrict__ cur, int* __restrict__ srcs)
{
    const int i = (blockIdx.x * 256 + threadIdx.x) * 4;
    if (i >= NE) return;
    const int4 t4 = *(const int4*)(ei + NE + i);
    const int4 s4 = *(const int4*)(ei + i);
    int pos;
    pos = offs[t4.x] + atomicAdd(&cur[t4.x], 1); srcs[pos] = s4.x;
    pos = offs[t4.y] + atomicAdd(&cur[t4.y], 1); srcs[pos] = s4.y;
    pos = offs[t4.z] + atomicAdd(&cur[t4.z], 1); srcs[pos] = s4.z;
    pos = offs[t4.w] + atomicAdd(&cur[t4.w], 1); srcs[pos] = s4.w;
}

// ---------------- per-node attention + aggregation (1 wave / node, fp16, fdot2) ----------------
// No max-subtraction (scores ~N(0,1); exp safe in fp32; softmax invariant).
// Score layout: lane = 4*jl + h. Agg layout: lane owns dims {2l,2l+1}, head hd=l>>4.
// V gathers issued at top of chunk; next chunk's srcs+K prefetched.
__global__ __launch_bounds__(256)
void attn_agg(const half_t* __restrict__ Qh, const half_t* __restrict__ Kh,
              const half_t* __restrict__ Vh, const int* __restrict__ offs,
              const int* __restrict__ srcs, half_t* __restrict__ AGG)
{
    const int lane = threadIdx.x & 63;
    const int t = blockIdx.x * 4 + (threadIdx.x >> 6);
    if (t >= N_NODES) return;
    const int off = offs[t];
    const int deg = offs[t + 1] - off;
    const int h  = lane & 3;
    const int jl = lane >> 2;
    const int hd = lane >> 4;
    const int d0 = lane * 2;

    half2_t q2[16];
    {
        const half_t* qp = Qh + (size_t)t * DIM + h * DH;
        #pragma unroll
        for (int i = 0; i < 4; ++i) {
            union { half8_t v8; half2_t v2[4]; } u;
            u.v8 = *(const half8_t*)(qp + i * 8);
            #pragma unroll
            for (int p = 0; p < 4; ++p) q2[i * 4 + p] = u.v2[p];
        }
    }

    float ssum = 0.f, acc0 = 0.f, acc1 = 0.f;
    const int nch = (deg + 15) >> 4;

    int sA = 0;
    half2_t kA[16] = {};
    {
        const int cnt0 = deg < 16 ? deg : 16;
        if (jl < cnt0) {
            sA = srcs[off + jl];
            const half_t* kp = Kh + (size_t)sA * DIM + h * DH;
            #pragma unroll
            for (int i = 0; i < 4; ++i) {
                union { half8_t v8; half2_t v2[4]; } u;
                u.v8 = *(const half8_t*)(kp + i * 8);
                #pragma unroll
                for (int p = 0; p < 4; ++p) kA[i * 4 + p] = u.v2[p];
            }
        }
    }

    for (int c = 0; c < nch; ++c) {
        const int base = c << 4;
        const int cnt = (deg - base) < 16 ? (deg - base) : 16;

        // V gathers first: 16 independent loads in flight during score math
        u32 vv[16];
        #pragma unroll
        for (int jj = 0; jj < 16; ++jj) {
            const int sj = __shfl(sA, jj * 4);          // readlane broadcast
            vv[jj] = *(const u32*)(Vh + (size_t)sj * DIM + d0);
        }

        // prefetch next chunk's srcs + K
        int sB = 0;
        half2_t kB[16] = {};
        if (c + 1 < nch) {
            const int rem = deg - base - 16;
            const int cntn = rem < 16 ? rem : 16;
            if (jl < cntn) {
                sB = srcs[off + base + 16 + jl];
                const half_t* kp = Kh + (size_t)sB * DIM + h * DH;
                #pragma unroll
                for (int i = 0; i < 4; ++i) {
                    union { half8_t v8; half2_t v2[4]; } u;
                    u.v8 = *(const half8_t*)(kp + i * 8);
                    #pragma unroll
                    for (int p = 0; p < 4; ++p) kB[i * 4 + p] = u.v2[p];
                }
            }
        }

        // score for this lane's (edge jl, head h): packed fp16 dot
        float dq = 0.f;
        #pragma unroll
        for (int p = 0; p < 16; ++p)
            dq = __builtin_amdgcn_fdot2(kA[p], q2[p], dq, false);
        const float e = (jl < cnt) ? __expf(dq * SCALEF) : 0.f;

        // per-head sum of e (lanes sharing h differ in bits 2..5)
        float se = e;
        #pragma unroll
        for (int w = 4; w < 64; w <<= 1) se += __shfl_xor(se, w);
        ssum += __shfl(se, hd);

        #pragma unroll
        for (int jj = 0; jj < 16; ++jj) {
            const float ejj = __shfl(e, jj * 4 + hd);
            union { u32 i; half2_t h2; } v;
            v.i = vv[jj];
            acc0 = fmaf(ejj, (float)v.h2[0], acc0);
            acc1 = fmaf(ejj, (float)v.h2[1], acc1);
        }

        sA = sB;
        #pragma unroll
        for (int p = 0; p < 16; ++p) kA[p] = kB[p];
    }

    const float inv = 1.0f / (ssum + 1e-10f);
    union { u32 i; half2_t h2; } o;
    o.h2[0] = (_Float16)(acc0 * inv);
    o.h2[1] = (_Float16)(acc1 * inv);
    *(u32*)(AGG + (size_t)t * DIM + d0) = o.i;
}

extern "C" void kernel_launch(void* const* d_in, const int* in_sizes, int n_in,
                              void* d_out, int out_size, void* d_ws, size_t ws_size,
                              hipStream_t stream)
{
    const float* X   = (const float*)d_in[0];
    const float* Wq  = (const float*)d_in[1];
    const float* bq  = (const float*)d_in[2];
    const float* Wk  = (const float*)d_in[3];
    const float* bk  = (const float*)d_in[4];
    const float* Wv  = (const float*)d_in[5];
    const float* bv  = (const float*)d_in[6];
    const float* Wo  = (const float*)d_in[7];
    const float* bo  = (const float*)d_in[8];
    const float* lng = (const float*)d_in[9];
    const float* lnb = (const float*)d_in[10];
    const int*   ei  = (const int*)d_in[11];
    float* out = (float*)d_out;

    const size_t ND = (size_t)N_NODES * DIM;   // 6.4M elems
    half_t* Qh   = (half_t*)d_ws;
    half_t* Kh   = Qh + ND;
    half_t* Vh   = Kh + ND;
    half_t* AGGh = Vh + ND;
    half_t* Wqh  = AGGh + ND;
    half_t* Wkh  = Wqh + DIM * DIM;
    half_t* Wvh  = Wkh + DIM * DIM;
    half_t* Woh  = Wvh + DIM * DIM;
    int* DEG  = (int*)(Woh + DIM * DIM);
    int* CUR  = DEG + N_NODES;
    int* OFFS = CUR + N_NODES;
    int* SRCS = OFFS + N_NODES + 1;
    int* BSUM = SRCS + NE;

    const int NB = (N_NODES + 1023) / 1024;   // 49

    hipMemsetAsync(DEG, 0, 2 * N_NODES * sizeof(int), stream);   // DEG + CUR

    // weights -> fp16 (one launch)
    f2h_w<<<dim3(8, 4), 256, 0, stream>>>(Wq, Wk, Wv, Wo, Wqh, Wkh, Wvh, Woh);

    // CSR build
    hist_kernel<<<(NE / 4 + 255) / 256, 256, 0, stream>>>(ei + NE, DEG);
    block_sums<<<NB, 256, 0, stream>>>(DEG, BSUM, N_NODES);
    scan_bsum<<<1, 64, 0, stream>>>(BSUM, OFFS + N_NODES, NB);
    block_scan<<<NB, 1024, 0, stream>>>(DEG, BSUM, OFFS, N_NODES);
    scatter_kernel<<<(NE / 4 + 255) / 256, 256, 0, stream>>>(ei, OFFS, CUR, SRCS);

    // projections (X converted to fp16 inline)
    const int gemmGrid = (N_NODES + 127) / 128;   // 391
    qkv_mfma<<<gemmGrid, 256, 0, stream>>>(X, Wqh, Wkh, Wvh, bq, bk, bv, Qh, Kh, Vh);

    // attention + aggregation
    attn_agg<<<(N_NODES + 3) / 4, 256, 0, stream>>>(Qh, Kh, Vh, OFFS, SRCS, AGGh);

    // output projection + residual + LayerNorm
    out_mfma_ln<<<gemmGrid, 256, 0, stream>>>(AGGh, Woh, bo, X, lng, lnb, out);
}

// Round 5
// 213.527 us; speedup vs baseline: 1.9071x; 1.0368x over previous
//
#include <hip/hip_runtime.h>

#define N_NODES 50000
#define DIM 128
#define NH 4
#define DH 32
#define NE 800000
#define SCALEF 0.17677669529663688f   // 1/sqrt(32)

typedef _Float16 half_t;
typedef __attribute__((ext_vector_type(2))) _Float16 half2_t;
typedef __attribute__((ext_vector_type(4))) _Float16 half4_t;
typedef __attribute__((ext_vector_type(8))) _Float16 half8_t;
typedef __attribute__((ext_vector_type(4))) float f32x4;
typedef unsigned short u16;
typedef unsigned int u32;

// ---------------- prep: weights->fp16 (blocks 0..31) + degree histogram (blocks 32..) ----------
__global__ __launch_bounds__(256)
void prep_kernel(const float* __restrict__ w0, const float* __restrict__ w1,
                 const float* __restrict__ w2, const float* __restrict__ w3,
                 half_t* __restrict__ o0, half_t* __restrict__ o1,
                 half_t* __restrict__ o2, half_t* __restrict__ o3,
                 const int* __restrict__ tgt, int* __restrict__ deg)
{
    if (blockIdx.x < 32) {
        const float* src; half_t* dst;
        switch (blockIdx.x >> 3) {
            case 0: src = w0; dst = o0; break;
            case 1: src = w1; dst = o1; break;
            case 2: src = w2; dst = o2; break;
            default: src = w3; dst = o3; break;
        }
        const int i = ((blockIdx.x & 7) * 256 + threadIdx.x) * 8;   // 16384 elems per weight
        const float4 a = *(const float4*)(src + i);
        const float4 b = *(const float4*)(src + i + 4);
        half8_t o;
        o[0] = (_Float16)a.x; o[1] = (_Float16)a.y; o[2] = (_Float16)a.z; o[3] = (_Float16)a.w;
        o[4] = (_Float16)b.x; o[5] = (_Float16)b.y; o[6] = (_Float16)b.z; o[7] = (_Float16)b.w;
        *(half8_t*)(dst + i) = o;
    } else {
        const int i = ((blockIdx.x - 32) * 256 + threadIdx.x) * 4;
        if (i >= NE) return;
        const int4 t4 = *(const int4*)(tgt + i);
        atomicAdd(&deg[t4.x], 1); atomicAdd(&deg[t4.y], 1);
        atomicAdd(&deg[t4.z], 1); atomicAdd(&deg[t4.w], 1);
    }
}

__global__ __launch_bounds__(256)
void block_sums(const int* __restrict__ deg, int* __restrict__ bsum, int n)
{
    __shared__ int acc4[4];
    const int b0 = blockIdx.x * 1024;
    int sum = 0;
    for (int i = threadIdx.x; i < 1024; i += 256) {
        const int g = b0 + i;
        sum += (g < n) ? deg[g] : 0;
    }
    #pragma unroll
    for (int w = 1; w < 64; w <<= 1) sum += __shfl_xor(sum, w);
    if ((threadIdx.x & 63) == 0) acc4[threadIdx.x >> 6] = sum;
    __syncthreads();
    if (threadIdx.x == 0) bsum[blockIdx.x] = acc4[0] + acc4[1] + acc4[2] + acc4[3];
}

__global__ void scan_bsum(int* __restrict__ bsum, int* __restrict__ offs_end, int nb)
{
    const int lane = threadIdx.x;           // 64 threads, 1 block
    const int v = (lane < nb) ? bsum[lane] : 0;
    int incl = v;
    #pragma unroll
    for (int w = 1; w < 64; w <<= 1) {
        const int t = __shfl_up(incl, w);
        if (lane >= w) incl += t;
    }
    if (lane < nb) bsum[lane] = incl - v;   // exclusive
    if (lane == 63) offs_end[0] = incl;     // total == NE
}

__global__ __launch_bounds__(1024)
void block_scan(const int* __restrict__ deg, const int* __restrict__ bsum,
                int* __restrict__ offs, int n)
{
    __shared__ int sh[1024];
    const int tid = threadIdx.x;
    const int gid = blockIdx.x * 1024 + tid;
    const int v = (gid < n) ? deg[gid] : 0;
    sh[tid] = v;
    __syncthreads();
    for (int ofs = 1; ofs < 1024; ofs <<= 1) {
        const int add = (tid >= ofs) ? sh[tid - ofs] : 0;
        __syncthreads();
        sh[tid] += add;
        __syncthreads();
    }
    if (gid < n) offs[gid] = bsum[blockIdx.x] + sh[tid] - v;
}

#define SCAT_NB 782   // ceil(NE/4/256)

// ---------------- fused: CSR scatter (blocks 0..781) + QKV MFMA GEMM (blocks 782..) ----------
__global__ __launch_bounds__(256)
void scat_qkv(const int* __restrict__ ei, const int* __restrict__ offs,
              int* __restrict__ cur, int* __restrict__ srcs,
              const float* __restrict__ X,
              const half_t* __restrict__ Wq, const half_t* __restrict__ Wk, const half_t* __restrict__ Wv,
              const float* __restrict__ bq, const float* __restrict__ bk, const float* __restrict__ bv,
              half_t* __restrict__ Qo, half_t* __restrict__ Ko, half_t* __restrict__ Vo)
{
    if (blockIdx.x < SCAT_NB) {
        const int i = (blockIdx.x * 256 + threadIdx.x) * 4;
        if (i >= NE) return;
        const int4 t4 = *(const int4*)(ei + NE + i);
        const int4 s4 = *(const int4*)(ei + i);
        int pos;
        pos = offs[t4.x] + atomicAdd(&cur[t4.x], 1); srcs[pos] = s4.x;
        pos = offs[t4.y] + atomicAdd(&cur[t4.y], 1); srcs[pos] = s4.y;
        pos = offs[t4.z] + atomicAdd(&cur[t4.z], 1); srcs[pos] = s4.z;
        pos = offs[t4.w] + atomicAdd(&cur[t4.w], 1); srcs[pos] = s4.w;
        return;
    }

    const int bid  = blockIdx.x - SCAT_NB;
    const int lane = threadIdx.x & 63;
    const int wv   = threadIdx.x >> 6;
    const int m0   = bid * 128 + wv * 32;
    const int cl   = lane & 15;           // node within group / W row within tile
    const int kg   = lane >> 4;           // k-slice

    half8_t bx[2][4];
    #pragma unroll
    for (int ng = 0; ng < 2; ++ng) {
        const int row = m0 + ng * 16 + cl;
        #pragma unroll
        for (int ks = 0; ks < 4; ++ks) {
            if (row < N_NODES) {
                const float* xp = X + (size_t)row * DIM + ks * 32 + kg * 8;
                const float4 x0 = *(const float4*)(xp);
                const float4 x1 = *(const float4*)(xp + 4);
                half8_t c;
                c[0] = (_Float16)x0.x; c[1] = (_Float16)x0.y; c[2] = (_Float16)x0.z; c[3] = (_Float16)x0.w;
                c[4] = (_Float16)x1.x; c[5] = (_Float16)x1.y; c[6] = (_Float16)x1.z; c[7] = (_Float16)x1.w;
                bx[ng][ks] = c;
            } else {
                bx[ng][ks] = (half8_t)(_Float16)0.0f;
            }
        }
    }

    const half_t* Ws[3] = {Wq, Wk, Wv};
    const float*  Bs[3] = {bq, bk, bv};
    half_t*       Os[3] = {Qo, Ko, Vo};

    #pragma unroll
    for (int o = 0; o < 3; ++o) {
        const half_t* W = Ws[o];
        half_t* O = Os[o];
        #pragma unroll
        for (int ct = 0; ct < 8; ++ct) {
            f32x4 acc0 = {0.f, 0.f, 0.f, 0.f};
            f32x4 acc1 = {0.f, 0.f, 0.f, 0.f};
            #pragma unroll
            for (int ks = 0; ks < 4; ++ks) {
                const half8_t a = *(const half8_t*)(W + (size_t)(ct * 16 + cl) * DIM + ks * 32 + kg * 8);
                acc0 = __builtin_amdgcn_mfma_f32_16x16x32_f16(a, bx[0][ks], acc0, 0, 0, 0);
                acc1 = __builtin_amdgcn_mfma_f32_16x16x32_f16(a, bx[1][ks], acc1, 0, 0, 0);
            }
            const int c0 = ct * 16 + kg * 4;            // this lane's 4 consecutive outcols
            const float4 b4 = *(const float4*)(Bs[o] + c0);
            const int n0 = m0 + cl;
            if (n0 < N_NODES) {
                half4_t hd4;
                hd4[0] = (_Float16)(acc0[0] + b4.x); hd4[1] = (_Float16)(acc0[1] + b4.y);
                hd4[2] = (_Float16)(acc0[2] + b4.z); hd4[3] = (_Float16)(acc0[3] + b4.w);
                *(half4_t*)(O + (size_t)n0 * DIM + c0) = hd4;
            }
            const int n1 = m0 + 16 + cl;
            if (n1 < N_NODES) {
                half4_t hd4;
                hd4[0] = (_Float16)(acc1[0] + b4.x); hd4[1] = (_Float16)(acc1[1] + b4.y);
                hd4[2] = (_Float16)(acc1[2] + b4.z); hd4[3] = (_Float16)(acc1[3] + b4.w);
                *(half4_t*)(O + (size_t)n1 * DIM + c0) = hd4;
            }
        }
    }
}

// ---------------- output GEMM + bias + residual + LayerNorm, transposed output ----------------
__global__ __launch_bounds__(256)
void out_mfma_ln(const half_t* __restrict__ Ah, const half_t* __restrict__ Wo,
                 const float* __restrict__ bo, const float* __restrict__ X,
                 const float* __restrict__ lng, const float* __restrict__ lnb,
                 float* __restrict__ out)
{
    const int lane = threadIdx.x & 63;
    const int wv   = threadIdx.x >> 6;
    const int m0   = blockIdx.x * 128 + wv * 32;
    const int cl   = lane & 15;
    const int kg   = lane >> 4;

    half8_t bx[2][4];
    #pragma unroll
    for (int ng = 0; ng < 2; ++ng) {
        const int row = m0 + ng * 16 + cl;
        #pragma unroll
        for (int ks = 0; ks < 4; ++ks) {
            if (row < N_NODES)
                bx[ng][ks] = *(const half8_t*)(Ah + (size_t)row * DIM + ks * 32 + kg * 8);
            else
                bx[ng][ks] = (half8_t)(_Float16)0.0f;
        }
    }

    float y[2][8][4];
    #pragma unroll
    for (int ct = 0; ct < 8; ++ct) {
        f32x4 acc0 = {0.f, 0.f, 0.f, 0.f};
        f32x4 acc1 = {0.f, 0.f, 0.f, 0.f};
        #pragma unroll
        for (int ks = 0; ks < 4; ++ks) {
            const half8_t a = *(const half8_t*)(Wo + (size_t)(ct * 16 + cl) * DIM + ks * 32 + kg * 8);
            acc0 = __builtin_amdgcn_mfma_f32_16x16x32_f16(a, bx[0][ks], acc0, 0, 0, 0);
            acc1 = __builtin_amdgcn_mfma_f32_16x16x32_f16(a, bx[1][ks], acc1, 0, 0, 0);
        }
        const int c0 = ct * 16 + kg * 4;
        const float4 b4 = *(const float4*)(bo + c0);
        const int n0 = m0 + cl;
        const int n1 = m0 + 16 + cl;
        float4 x0 = make_float4(0.f, 0.f, 0.f, 0.f), x1 = x0;
        if (n0 < N_NODES) x0 = *(const float4*)(X + (size_t)n0 * DIM + c0);
        if (n1 < N_NODES) x1 = *(const float4*)(X + (size_t)n1 * DIM + c0);
        y[0][ct][0] = acc0[0] + b4.x + x0.x; y[0][ct][1] = acc0[1] + b4.y + x0.y;
        y[0][ct][2] = acc0[2] + b4.z + x0.z; y[0][ct][3] = acc0[3] + b4.w + x0.w;
        y[1][ct][0] = acc1[0] + b4.x + x1.x; y[1][ct][1] = acc1[1] + b4.y + x1.y;
        y[1][ct][2] = acc1[2] + b4.z + x1.z; y[1][ct][3] = acc1[3] + b4.w + x1.w;
    }

    // LayerNorm: node (ng,cl)'s 128 cols live in the 4 lanes sharing cl (kg=0..3), 32 vals each
    #pragma unroll
    for (int ng = 0; ng < 2; ++ng) {
        float s = 0.f, sq = 0.f;
        #pragma unroll
        for (int ct = 0; ct < 8; ++ct)
            #pragma unroll
            for (int j = 0; j < 4; ++j) { const float v = y[ng][ct][j]; s += v; sq += v * v; }
        s += __shfl_xor(s, 16); sq += __shfl_xor(sq, 16);
        s += __shfl_xor(s, 32); sq += __shfl_xor(sq, 32);
        const float mu   = s * (1.0f / 128.0f);
        const float var  = sq * (1.0f / 128.0f) - mu * mu;
        const float rstd = rsqrtf(var + 1e-5f);
        const int node = m0 + ng * 16 + cl;
        if (node < N_NODES) {
            #pragma unroll
            for (int ct = 0; ct < 8; ++ct) {
                const int c0 = ct * 16 + kg * 4;
                const float4 g4 = *(const float4*)(lng + c0);
                const float4 l4 = *(const float4*)(lnb + c0);
                float4 ov;
                ov.x = g4.x * (y[ng][ct][0] - mu) * rstd + l4.x;
                ov.y = g4.y * (y[ng][ct][1] - mu) * rstd + l4.y;
                ov.z = g4.z * (y[ng][ct][2] - mu) * rstd + l4.z;
                ov.w = g4.w * (y[ng][ct][3] - mu) * rstd + l4.w;
                *(float4*)(out + (size_t)node * DIM + c0) = ov;
            }
        }
    }
}

// ---------------- per-node attention + aggregation (1 wave / node, fp16) ----------------
// No max-subtraction (scores ~N(0,1); exp safe; softmax invariant).
// Score layout: lane = 4*jl + h (16 edges x 4 heads).
// Agg layout: half-wave w = lane>>5 handles edges j%2==w; lane owns 4 dims
//   dl4*4..+3 (dl4 = lane&31, head hq = dl4>>3); V gathered as 8B half4 (2 edges/instr);
//   e broadcast as packed half2; v_pk_fma_f16 accumulate; cross-half combine at end.
__global__ __launch_bounds__(256)
void attn_agg(const half_t* __restrict__ Qh, const half_t* __restrict__ Kh,
              const half_t* __restrict__ Vh, const int* __restrict__ offs,
              const int* __restrict__ srcs, half_t* __restrict__ AGG)
{
    const int lane = threadIdx.x & 63;
    const int t = blockIdx.x * 4 + (threadIdx.x >> 6);
    if (t >= N_NODES) return;
    const int off = offs[t];
    const int deg = offs[t + 1] - off;
    const int h  = lane & 3;
    const int jl = lane >> 2;
    const int w  = lane >> 5;
    const int dl4 = lane & 31;
    const int hq  = dl4 >> 3;

    half2_t q2[16];
    {
        const half_t* qp = Qh + (size_t)t * DIM + h * DH;
        #pragma unroll
        for (int i = 0; i < 4; ++i) {
            union { half8_t v8; half2_t v2[4]; } u;
            u.v8 = *(const half8_t*)(qp + i * 8);
            #pragma unroll
            for (int p = 0; p < 4; ++p) q2[i * 4 + p] = u.v2[p];
        }
    }

    float ssumL = 0.f;                       // per-lane (score layout)
    half2_t a0 = (half2_t)(_Float16)0.0f;    // dims dl4*4, dl4*4+1
    half2_t a1 = (half2_t)(_Float16)0.0f;    // dims dl4*4+2, dl4*4+3
    const int nch = (deg + 15) >> 4;

    int sA = 0;
    half2_t kA[16] = {};
    {
        const int cnt0 = deg < 16 ? deg : 16;
        if (jl < cnt0) {
            sA = srcs[off + jl];
            const half_t* kp = Kh + (size_t)sA * DIM + h * DH;
            #pragma unroll
            for (int i = 0; i < 4; ++i) {
                union { half8_t v8; half2_t v2[4]; } u;
                u.v8 = *(const half8_t*)(kp + i * 8);
                #pragma unroll
                for (int p = 0; p < 4; ++p) kA[i * 4 + p] = u.v2[p];
            }
        }
    }

    for (int c = 0; c < nch; ++c) {
        const int base = c << 4;
        const int cnt = (deg - base) < 16 ? (deg - base) : 16;

        // prefetch next chunk's srcs + K
        int sB = 0;
        half2_t kB[16] = {};
        if (c + 1 < nch) {
            const int rem = deg - base - 16;
            const int cntn = rem < 16 ? rem : 16;
            if (jl < cntn) {
                sB = srcs[off + base + 16 + jl];
                const half_t* kp = Kh + (size_t)sB * DIM + h * DH;
                #pragma unroll
                for (int i = 0; i < 4; ++i) {
                    union { half8_t v8; half2_t v2[4]; } u;
                    u.v8 = *(const half8_t*)(kp + i * 8);
                    #pragma unroll
                    for (int p = 0; p < 4; ++p) kB[i * 4 + p] = u.v2[p];
                }
            }
        }

        // score for this lane's (edge jl, head h): packed fp16 dot
        float dq = 0.f;
        #pragma unroll
        for (int p = 0; p < 16; ++p)
            dq = __builtin_amdgcn_fdot2(kA[p], q2[p], dq, false);
        const float e = (jl < cnt) ? __expf(dq * SCALEF) : 0.f;
        ssumL += e;

        // packed (e,e) for broadcast
        union { u32 u; half2_t h2; } pe;
        const _Float16 eh = (_Float16)e;
        pe.h2[0] = eh; pe.h2[1] = eh;
        const int peI = (int)pe.u;

        // aggregate: 8 x half4 loads, 2 edges per load instr
        #pragma unroll
        for (int i = 0; i < 8; ++i) {
            const int j = 2 * i + w;                     // this half-wave's edge
            const int sj = __shfl(sA, j * 4);
            union { u32 u; half2_t h2; } e2;
            e2.u = (u32)__shfl(peI, 8 * i + 4 * w + hq);
            union { half4_t v4; half2_t h2[2]; } v;
            v.v4 = *(const half4_t*)(Vh + (size_t)sj * DIM + dl4 * 4);
            a0 = e2.h2 * v.h2[0] + a0;
            a1 = e2.h2 * v.h2[1] + a1;
        }

        sA = sB;
        #pragma unroll
        for (int p = 0; p < 16; ++p) kA[p] = kB[p];
    }

    // combine the two half-waves (lane l and l^32 hold the same dims)
    {
        union { u32 u; half2_t h2; } c0, c1;
        c0.h2 = a0; c1.h2 = a1;
        union { u32 u; half2_t h2; } d0x, d1x;
        d0x.u = (u32)__shfl_xor((int)c0.u, 32);
        d1x.u = (u32)__shfl_xor((int)c1.u, 32);
        a0 = a0 + d0x.h2;
        a1 = a1 + d1x.h2;
    }

    // denominator: reduce ssumL over bits 2..5 (lanes sharing h), broadcast head hq
    float se = ssumL;
    #pragma unroll
    for (int ww = 4; ww < 64; ww <<= 1) se += __shfl_xor(se, ww);
    const float sh = __shfl(se, hq);
    const float inv = 1.0f / (sh + 1e-10f);

    if (lane < 32) {
        half4_t o;
        o[0] = (_Float16)((float)a0[0] * inv);
        o[1] = (_Float16)((float)a0[1] * inv);
        o[2] = (_Float16)((float)a1[0] * inv);
        o[3] = (_Float16)((float)a1[1] * inv);
        *(half4_t*)(AGG + (size_t)t * DIM + dl4 * 4) = o;
    }
}

extern "C" void kernel_launch(void* const* d_in, const int* in_sizes, int n_in,
                              void* d_out, int out_size, void* d_ws, size_t ws_size,
                              hipStream_t stream)
{
    const float* X   = (const float*)d_in[0];
    const float* Wq  = (const float*)d_in[1];
    const float* bq  = (const float*)d_in[2];
    const float* Wk  = (const float*)d_in[3];
    const float* bk  = (const float*)d_in[4];
    const float* Wv  = (const float*)d_in[5];
    const float* bv  = (const float*)d_in[6];
    const float* Wo  = (const float*)d_in[7];
    const float* bo  = (const float*)d_in[8];
    const float* lng = (const float*)d_in[9];
    const float* lnb = (const float*)d_in[10];
    const int*   ei  = (const int*)d_in[11];
    float* out = (float*)d_out;

    const size_t ND = (size_t)N_NODES * DIM;   // 6.4M elems
    half_t* Qh   = (half_t*)d_ws;
    half_t* Kh   = Qh + ND;
    half_t* Vh   = Kh + ND;
    half_t* AGGh = Vh + ND;
    half_t* Wqh  = AGGh + ND;
    half_t* Wkh  = Wqh + DIM * DIM;
    half_t* Wvh  = Wkh + DIM * DIM;
    half_t* Woh  = Wvh + DIM * DIM;
    int* DEG  = (int*)(Woh + DIM * DIM);
    int* CUR  = DEG + N_NODES;
    int* OFFS = CUR + N_NODES;
    int* SRCS = OFFS + N_NODES + 1;
    int* BSUM = SRCS + NE;

    const int NB = (N_NODES + 1023) / 1024;   // 49

    hipMemsetAsync(DEG, 0, 2 * N_NODES * sizeof(int), stream);   // DEG + CUR

    // weights -> fp16 + degree histogram (one launch)
    prep_kernel<<<32 + SCAT_NB, 256, 0, stream>>>(Wq, Wk, Wv, Wo, Wqh, Wkh, Wvh, Woh,
                                                  ei + NE, DEG);

    block_sums<<<NB, 256, 0, stream>>>(DEG, BSUM, N_NODES);
    scan_bsum<<<1, 64, 0, stream>>>(BSUM, OFFS + N_NODES, NB);
    block_scan<<<NB, 1024, 0, stream>>>(DEG, BSUM, OFFS, N_NODES);

    // CSR scatter + QKV projections (one launch; independent block ranges)
    const int gemmGrid = (N_NODES + 127) / 128;   // 391
    scat_qkv<<<SCAT_NB + gemmGrid, 256, 0, stream>>>(ei, OFFS, CUR, SRCS,
                                                     X, Wqh, Wkh, Wvh, bq, bk, bv,
                                                     Qh, Kh, Vh);

    // attention + aggregation
    attn_agg<<<(N_NODES + 3) / 4, 256, 0, stream>>>(Qh, Kh, Vh, OFFS, SRCS, AGGh);

    // output projection + residual + LayerNorm
    out_mfma_ln<<<gemmGrid, 256, 0, stream>>>(AGGh, Woh, bo, X, lng, lnb, out);
}